// Round 2
// baseline (562.969 us; speedup 1.0000x reference)
//
#include <hip/hip_runtime.h>
#include <hip/hip_bf16.h>

#define HW 512

typedef __attribute__((ext_vector_type(8))) short bf16x8;
typedef __attribute__((ext_vector_type(16))) float floatx16;

union BFrag { uint2 u2[2]; bf16x8 v; };

static __device__ inline ushort f2bf(float f) {
    __hip_bfloat16 h = __float2bfloat16(f);
    return *(ushort*)&h;
}

// Pre-packed A fragments (filters), built once by prep_afrag:
//   frag index = AOFF + s*256 + tid   (16 B each, coalesced per step)
// sizes: scale0 18, scale1 27, scale2 30 steps -> 75*256 frags = 307 KB.
__device__ __align__(16) short g_afrag[(18 + 27 + 30) * 256 * 8];

// ---------------------------------------------------------------------------
// Implicit-GEMM grouped directional conv on mfma_f32_32x32x16_bf16.
//   M = 32 = NDIR dirs x YPACK output rows (YPACK = 32/NDIR)
//   N = 32 pixels, strided by 4: px = gx0 + r + 4n, phase r = wave id (0..3)
//   K = 16 taps per step = 2 octets (dyu row, 8-consecutive-dx), the dx
//       window shifted by -r inside the A fragment so B addresses are
//       phase-independent and 8B-aligned (ds_read_b64).
// A[m=lane&31][k=(lane>>5)*8+j]; B[k=(lane>>5)*8+j][n=lane&31];
// D: col=lane&31, row=(reg&3)+8*(reg>>2)+4*(lane>>5)   (m74/m101 verified).
//
// R2: 32x32x16 shape (halves LDS traffic per output, 4x outputs/MFMA);
// A-fragments precomputed once into g_afrag by prep kernel (removes the
// ~30%-of-issue branchy per-block A build); step-outer / CB=4-chain-inner
// loop gives 4 independent accumulators (MFMA ILP) with 1 A-frag live.
// ---------------------------------------------------------------------------
template<int K, int NDIR, int SUB0, int OCTS, int NSTEP, int AOFF>
__device__ __forceinline__
void conv_body(ushort* __restrict__ s_img,
               const float* __restrict__ img, float* __restrict__ out,
               const int plane)
{
    constexpr int YPACK   = 32 / NDIR;
    constexpr int R       = K / 2;
    constexpr int TILE_W  = 128, TILE_H = 32;
    constexpr int NCHAIN  = TILE_H / YPACK;
    constexpr int CB      = 4;                 // chains per pass (indep. accs)
    constexpr int NPASS   = NCHAIN / CB;       // s0:1 s1:2 s2:4
    constexpr int ROWS_A  = K + YPACK - 1;     // dyu rows spanned by taps
    constexpr int EXT_Y   = (TILE_H - YPACK) + ROWS_A;
    constexpr int EXT_X   = 4 * 31 + 8 * (OCTS - 1) + 8;
    constexpr int SPX     = (EXT_X + 7) & ~7;  // row stride (mult of 8 elems)
    constexpr int P       = (OCTS == 3) ? 3 : 1;   // addr period in steps
    constexpr int GSTRIDE = (2 * P / OCTS) * SPX;  // elems per step-group
    constexpr int NG      = NSTEP / P;
    static_assert(NSTEP % P == 0, "octet chunking must be exact");
    static_assert(NSTEP * 2 == ROWS_A * OCTS, "step count must cover octets");

    const int tid   = threadIdx.x;
    const int bx    = blockIdx.x, by = blockIdx.y;
    const int bb    = plane / 3, cc = plane % 3;
    const float* __restrict__ src = img + (size_t)plane * HW * HW;
    const int gx0 = bx * TILE_W, gy0 = by * TILE_H;

    // ---- stage image tile as bf16 (zero-filled OOB; pad cols defined) ----
    constexpr int PAIRS = SPX / 2;
    for (int idx = tid; idx < EXT_Y * PAIRS; idx += 256) {
        const int row = idx / PAIRS;
        const int col = (idx - row * PAIRS) * 2;
        const int gy = gy0 - R + row;
        const int gx = gx0 - R + col;
        float v0 = 0.f, v1 = 0.f;
        if ((unsigned)gy < HW) {
            if ((unsigned)gx       < HW) v0 = src[gy * HW + gx];
            if ((unsigned)(gx + 1) < HW) v1 = src[gy * HW + gx + 1];
        }
        *(uint*)&s_img[row * SPX + col] = ((uint)f2bf(v1) << 16) | (uint)f2bf(v0);
    }
    __syncthreads();

    const int lane = tid & 63;
    const int r    = tid >> 6;                 // wave id = pixel phase
    const int n    = lane & 31;                // n for B / col of D
    const int h    = lane >> 5;                // k-half

    // per-lane base offsets (elements) for s % P = 0..P-1, pass base 0
    int base0[P];
    #pragma unroll
    for (int s0 = 0; s0 < P; ++s0) {
        const int c0   = 2 * s0 + h;           // octet id
        const int dyu0 = c0 / OCTS, o0 = c0 - dyu0 * OCTS;
        base0[s0] = dyu0 * SPX + 8 * o0 + 4 * n;   // 8B-aligned: SPX%8==0
    }

    const int px = gx0 + r + 4 * n;
    const short* __restrict__ abase = g_afrag + ((size_t)AOFF + tid) * 8;

    for (int p = 0; p < NPASS; ++p) {
        floatx16 acc[CB] = {};
        const ushort* bp = s_img + p * (CB * YPACK * SPX);
        const short*  ap = abase;
        for (int gi = 0; gi < NG; ++gi) {
            #pragma unroll
            for (int s0 = 0; s0 < P; ++s0) {
                const bf16x8 a = *(const bf16x8*)(ap + s0 * 256 * 8);
                #pragma unroll
                for (int i = 0; i < CB; ++i) {
                    const ushort* q = bp + (base0[s0] + i * (YPACK * SPX));
                    BFrag b;
                    b.u2[0] = *(const uint2*)q;
                    b.u2[1] = *(const uint2*)(q + 4);
                    acc[i] = __builtin_amdgcn_mfma_f32_32x32x16_bf16(a, b.v, acc[i], 0, 0, 0);
                }
            }
            bp += GSTRIDE;
            ap += P * 256 * 8;
        }
        #pragma unroll
        for (int i = 0; i < CB; ++i) {
            #pragma unroll
            for (int reg = 0; reg < 16; ++reg) {
                const int m  = (reg & 3) + 8 * (reg >> 2) + 4 * h;
                const int dd = m & (NDIR - 1);
                const int yo = m / NDIR;
                const int Y  = gy0 + (p * CB + i) * YPACK + yo;
                out[((size_t)(bb * 87 + cc * 29 + SUB0 + dd) * HW + Y) * HW + px] = acc[i][reg];
            }
        }
    }
}

// Max staged-tile footprint (elems): s0 42*144=6048, s1 46*152=6992,
// s2 50*152=7600 -> 15.2 KB.
#define SMEM_ELEMS 7600

__global__ __launch_bounds__(256, 4)
void fused_conv(const float* __restrict__ img, float* __restrict__ out)
{
    __shared__ __align__(16) ushort s_img[SMEM_ELEMS];
    const int z  = blockIdx.z;
    const int sc = z % 3;                      // heavy scale first in dispatch
    const int plane = z / 3;
    if (sc == 0) {
        conv_body<19, 16, 12, 3, 30, (18 + 27) * 256>(s_img, img, out, plane);
    } else if (sc == 1) {
        conv_body<15,  8,  4, 3, 27, 18 * 256>(s_img, img, out, plane);
    } else {
        conv_body<11,  4,  0, 2, 18, 0>(s_img, img, out, plane);
    }
}

// ---------------------------------------------------------------------------
// A-fragment prep: one block per scale, 256 threads; each thread packs its
// NSTEP bf16x8 fragments (phase-shifted, zero-padded filter taps).
// ---------------------------------------------------------------------------
template<int K, int NDIR, int OCTS, int NSTEP, int AOFF>
__device__ __forceinline__
void prep_body(const float* __restrict__ filt)
{
    const int tid  = threadIdx.x;
    const int lane = tid & 63, r = tid >> 6;
    const int m    = lane & 31, h = lane >> 5;
    const int dirm  = m & (NDIR - 1);
    const int yoffm = m / NDIR;
    for (int s = 0; s < NSTEP; ++s) {
        bf16x8 v;
        #pragma unroll
        for (int j = 0; j < 8; ++j) {
            const int c   = 2 * s + h;
            const int dyu = c / OCTS, o = c - dyu * OCTS;
            const int dy  = dyu - yoffm;
            const int dx  = 8 * o + j - r;
            float fv = 0.f;
            if (dy >= 0 && dy < K && dx >= 0 && dx < K)
                fv = filt[(dirm * K + dy) * K + dx];
            v[j] = (short)f2bf(fv);
        }
        *(bf16x8*)&g_afrag[((size_t)AOFF + s * 256 + tid) * 8] = v;
    }
}

__global__ __launch_bounds__(256)
void prep_afrag(const float* __restrict__ f0, const float* __restrict__ f1,
                const float* __restrict__ f2)
{
    if (blockIdx.x == 0)      prep_body<11,  4, 2, 18, 0>(f0);
    else if (blockIdx.x == 1) prep_body<15,  8, 3, 27, 18 * 256>(f1);
    else                      prep_body<19, 16, 3, 30, (18 + 27) * 256>(f2);
}

// ---------------------------------------------------------------------------
// Low channel: 4x4 avg-pool + 4x bilinear upsample (half-pixel, edge clamp).
// ---------------------------------------------------------------------------
__global__ __launch_bounds__(256)
void low_kernel(const float* __restrict__ img, float* __restrict__ out)
{
    __shared__ float s_p[34 * 35];
    const int tid   = threadIdx.x;
    const int bx    = blockIdx.x, by = blockIdx.y;
    const int plane = blockIdx.z;
    const int b     = plane / 3, c = plane % 3;
    const float* __restrict__ src = img + (size_t)plane * HW * HW;
    const int lx0 = bx * 32, ly0 = by * 32;

    for (int idx = tid; idx < 34 * 34; idx += 256) {
        const int r = idx / 34, col = idx % 34;
        const int ly = min(max(ly0 - 1 + r,   0), 127);
        const int lx = min(max(lx0 - 1 + col, 0), 127);
        const float* p = src + (size_t)(ly * 4) * HW + lx * 4;
        float s = 0.f;
        #pragma unroll
        for (int rr = 0; rr < 4; ++rr) {
            const float4 v = *(const float4*)(p + (size_t)rr * HW);
            s += v.x + v.y + v.z + v.w;
        }
        s_p[r * 35 + col] = s * (1.f / 16.f);
    }
    __syncthreads();

    const size_t outbase = (size_t)(b * 87 + c * 29 + 28) * HW * HW;
    for (int k = 0; k < 64; ++k) {
        const int pix = tid + k * 256;
        const int ry = pix >> 7, rx = pix & 127;
        const int gy = ly0 * 4 + ry, gx = lx0 * 4 + rx;
        const float cy = (gy - 1.5f) * 0.25f;
        const float cx = (gx - 1.5f) * 0.25f;
        const int jy = (int)floorf(cy), jx = (int)floorf(cx);
        const float fy = cy - jy, fx = cx - jx;
        const int tyy = jy - (ly0 - 1);
        const int txx = jx - (lx0 - 1);
        const float p00 = s_p[tyy * 35 + txx],       p01 = s_p[tyy * 35 + txx + 1];
        const float p10 = s_p[(tyy + 1) * 35 + txx], p11 = s_p[(tyy + 1) * 35 + txx + 1];
        const float v0 = p00 + fx * (p01 - p00);
        const float v1 = p10 + fx * (p11 - p10);
        out[outbase + (size_t)gy * HW + gx] = v0 + fy * (v1 - v0);
    }
}

extern "C" void kernel_launch(void* const* d_in, const int* in_sizes, int n_in,
                              void* d_out, int out_size, void* d_ws, size_t ws_size,
                              hipStream_t stream)
{
    const float* img = (const float*)d_in[0];
    const float* f0  = (const float*)d_in[1];
    const float* f1  = (const float*)d_in[2];
    const float* f2  = (const float*)d_in[3];
    float* out = (float*)d_out;

    dim3 block(256);
    prep_afrag<<<dim3(3), block, 0, stream>>>(f0, f1, f2);
    // z = plane*3 + {scale2, scale1, scale0} : heavy blocks dispatched early.
    fused_conv<<<dim3(HW / 128, HW / 32, 36), block, 0, stream>>>(img, out);
    low_kernel<<<dim3(4, 4, 12), block, 0, stream>>>(img, out);
}